// Round 14
// baseline (51.265 us; speedup 1.0000x reference)
//
#include <hip/hip_runtime.h>
#include <hip/hip_bf16.h>

// RippleNetPlus — round 14: two-kernel split.
// K_A rh_gemv: 131072 independent 32x32 matvecs (Rh = R[r] @ h), one per
//   half-wave, 16384 blocks, no LDS/barriers, ~40 VGPR -> 32 waves/CU and a
//   saturated L2 pipe (TLP hides latency where the allocator wouldn't).
//   Writes Rh to d_ws in task order (== index-array order), coalesced.
// K_B ripple_main: R13 minus phase A; stages Rh from ws (16 b128/block)
//   inside the existing init barrier. Phases B/C/D/E byte-identical to R13.
// Fallback: if ws_size < 16.8MB, launch the R13 fused kernel.

#define NHOP 2

typedef __attribute__((ext_vector_type(4)))  float f32x4;
typedef __attribute__((ext_vector_type(8)))  short bf16x8s;
typedef __attribute__((ext_vector_type(4)))  int   i32x4;

__device__ __forceinline__ float sigmoid_f(float x){ return 1.0f/(1.0f+__expf(-x)); }
__device__ __forceinline__ float tanh_f(float x){
  float e = __expf(2.0f*x);
  return 1.0f - 2.0f/(e + 1.0f);
}
__device__ __forceinline__ unsigned pk_bf16(float lo, float hi){
  __hip_bfloat162 h = __float22bfloat162_rn(make_float2(lo, hi));
  return *reinterpret_cast<unsigned*>(&h);
}
__device__ __forceinline__ float bfly8(float p[8], bool bb4, bool bb2, bool bb1){
  #pragma unroll
  for (int k = 0; k < 4; ++k){
    float send = bb4 ? p[k] : p[k+4];
    float t = __shfl_xor(send, 4);
    p[k] = (bb4 ? p[k+4] : p[k]) + t;
  }
  #pragma unroll
  for (int k = 0; k < 2; ++k){
    float send = bb2 ? p[k] : p[k+2];
    float t = __shfl_xor(send, 2);
    p[k] = (bb2 ? p[k+2] : p[k]) + t;
  }
  float send = bb1 ? p[0] : p[1];
  float t = __shfl_xor(send, 1);
  return (bb1 ? p[1] : p[0]) + t;
}

// ---------------- K_A: Rh gather-matvec, one task per half-wave ----------------
__global__ __launch_bounds__(256) void rh_gemv(
    const int* __restrict__ h_i, const int* __restrict__ R_i,
    const float* __restrict__ entity_emb, const float* __restrict__ relation_emb,
    float* __restrict__ ws, int ntask)
{
  const int hw = (blockIdx.x*256 + threadIdx.x) >> 5;   // task id
  if (hw >= ntask) return;
  const int o  = threadIdx.x & 31;
  const int c  = o & 7;
  const int r_ = o >> 3;
  const bool bb4 = (c & 4) != 0;
  const bool bb2 = (c & 2) != 0;
  const bool bb1 = (c & 1) != 0;

  const int ridx = R_i[hw];          // index arrays are already in task order
  const int hidx = h_i[hw];
  const float* Rbase = relation_emb + (size_t)ridx*1024;
  float4 hv = *(const float4*)(entity_emb + (size_t)hidx*32 + c*4);
  float p[8];
  #pragma unroll
  for (int q = 0; q < 8; ++q){
    float4 rv = *(const float4*)(Rbase + q*128 + o*4);
    p[q] = rv.x*hv.x + rv.y*hv.y + rv.z*hv.z + rv.w*hv.w;
  }
  float a = bfly8(p, bb4, bb2, bb1);
  ws[(size_t)hw*32 + (c*4 + r_)] = a;   // lane->row bijective, 128B coalesced
}

// ---------------- K_B: main pipeline (R13 minus phase A) ----------------
__global__ __launch_bounds__(256) void ripple_main(
    const int* __restrict__ t_i, const int* __restrict__ v_i,
    const float* __restrict__ entity_emb,
    const float* __restrict__ agg_w1, const float* __restrict__ agg_b1,
    const float* __restrict__ agg_w2,
    const float* __restrict__ gru_w_ih, const float* __restrict__ gru_w_hh,
    const float* __restrict__ gru_b_ih, const float* __restrict__ gru_b_hh,
    const float* __restrict__ ans_w, const float* __restrict__ ans_b,
    const float* __restrict__ ws,
    float* __restrict__ out, int batch)
{
  __shared__ __align__(16) int   s_bfrag[8*64*4];     // 8 KB   shared B-frags
  __shared__ __align__(16) float s_rhA[2][2][32*33];  // 16.5KB [elem][hop] stride-33
  __shared__ __align__(16) float s_vsM[2][64];        // [elem][i*2+{vs,M}]
  __shared__ __align__(16) float s_zpart[2][64];      // [elem][ot*32+m]
  __shared__ __align__(16) float s_opart[2][4*32];    // [elem][w][o]
  __shared__ __align__(16) float s_M[2][32];
  __shared__ __align__(16) float s_gig[2][192];       // [elem] gi[0:96] gh[96:192]

  const int bid = blockIdx.x;
  const int eA  = bid*2;
  const int eB  = (eA + 1 < batch) ? eA + 1 : eA;
  const int tid = threadIdx.x;
  const int g   = tid >> 5;   // group 0..7
  const int o   = tid & 31;
  const int l   = tid & 63;   // lane
  const int w   = tid >> 6;   // wave 0..3

  // ---- init: stage B-fragments (16x16x32 layout; same as R10..R13) ----
  #pragma unroll
  for (int k = 0; k < 2; ++k){
    int s  = tid + k*256;           // 0..511
    int f  = s >> 6, li = s & 63;
    int x  = f >> 1, otf = f & 1;
    const float* src = agg_w1 + (otf*16 + (li & 15))*128 + x*32 + ((li >> 4) & 3)*8;
    float4 f0 = *(const float4*)src;
    float4 f1 = *(const float4*)(src + 4);
    *(int4*)&s_bfrag[s*4] = make_int4((int)pk_bf16(f0.x, f0.y), (int)pk_bf16(f0.z, f0.w),
                                      (int)pk_bf16(f1.x, f1.y), (int)pk_bf16(f1.z, f1.w));
  }
  if (tid < 64){
    int e  = tid >> 5, oo = tid & 31;
    float v = entity_emb[(size_t)v_i[e ? eB : eA]*32 + oo];
    s_vsM[e][oo*2+0] = v; s_vsM[e][oo*2+1] = v; s_M[e][oo] = v;
  }

  // ---- stage Rh from ws into stride-33 LDS (coalesced b128 reads) ----
  {
    const float4* wsA = (const float4*)(ws + (size_t)eA*NHOP*32*32);
    const float4* wsB = (const float4*)(ws + (size_t)eB*NHOP*32*32);
    #pragma unroll
    for (int k = 0; k < 2; ++k){
      int f    = tid + k*256;       // float4 id 0..511 within one elem (2 hops)
      int task = f >> 3;            // 0..63 : hp*32 + m
      int i4   = f & 7;
      int hp   = task >> 5, m = task & 31;
      float4 va = wsA[f];
      float4 vb = wsB[f];
      *(float4*)&s_rhA[0][hp][m*33 + i4*4] = va;
      *(float4*)&s_rhA[1][hp][m*33 + i4*4] = vb;
    }
  }
  __syncthreads();

  // per-wave tile coords (phase B) + hop-invariant B-fragments in registers
  const int mt  = w >> 1, ot = w & 1;
  const int col = l & 15;
  const int kg  = l >> 4;
  const float b1o = agg_b1[ot*16 + col];
  const float w2o = agg_w2[ot*16 + col];
  i32x4 bv[4];
  #pragma unroll
  for (int x = 0; x < 4; ++x)
    bv[x] = *(const i32x4*)&s_bfrag[((x*2 + ot)*64 + l)*4];

  for (int hop = 0; hop < NHOP; ++hop){
    // ---- t-row prefetch for both elements ----
    float tvA[4], tvB[4];
    #pragma unroll
    for (int ml = 0; ml < 4; ++ml){
      tvA[ml] = entity_emb[(size_t)t_i[(eA*NHOP + hop)*32 + g*4 + ml]*32 + o];
      tvB[ml] = entity_emb[(size_t)t_i[(eB*NHOP + hop)*32 + g*4 + ml]*32 + o];
    }

    // ---- phase B: wave tile via mfma_16x16x32, both elements ----
    {
      #pragma unroll
      for (int e = 0; e < 2; ++e){
        const float* rp = &s_rhA[e][hop][(mt*16 + col)*33 + kg*8];
        float4 q0 = *(const float4*)(rp);
        float4 q1 = *(const float4*)(rp + 4);
        float rh[8] = {q0.x,q0.y,q0.z,q0.w,q1.x,q1.y,q1.z,q1.w};
        unsigned aw[4][4];
        #pragma unroll
        for (int q = 0; q < 4; ++q){
          int i0 = kg*8 + 2*q;
          float2 vm0 = *(const float2*)&s_vsM[e][i0*2];
          float2 vm1 = *(const float2*)&s_vsM[e][(i0+1)*2];
          float e0 = rh[2*q], e1 = rh[2*q+1];
          aw[0][q] = pk_bf16(e0*vm0.x,        e1*vm1.x);
          aw[1][q] = pk_bf16(e0*vm0.y,        e1*vm1.y);
          aw[2][q] = pk_bf16(fabsf(e0-vm0.x), fabsf(e1-vm1.x));
          aw[3][q] = pk_bf16(fabsf(e0-vm0.y), fabsf(e1-vm1.y));
        }
        f32x4 acc = {0.f, 0.f, 0.f, 0.f};
        #pragma unroll
        for (int x = 0; x < 4; ++x){
          i32x4 av = {(int)aw[x][0], (int)aw[x][1], (int)aw[x][2], (int)aw[x][3]};
          acc = __builtin_amdgcn_mfma_f32_16x16x32_bf16(
                  __builtin_bit_cast(bf16x8s, av),
                  __builtin_bit_cast(bf16x8s, bv[x]), acc, 0, 0, 0);
        }
        float v[4];
        #pragma unroll
        for (int r = 0; r < 4; ++r) v[r] = tanh_f(acc[r] + b1o) * w2o;
        const bool b3 = (l & 8) != 0;
        #pragma unroll
        for (int k = 0; k < 2; ++k){
          float send = b3 ? v[k] : v[k+2];
          float tt = __shfl_xor(send, 8);
          v[k] = (b3 ? v[k+2] : v[k]) + tt;
        }
        const bool b2_ = (l & 4) != 0;
        {
          float send = b2_ ? v[0] : v[1];
          float tt = __shfl_xor(send, 4);
          v[0] = (b2_ ? v[1] : v[0]) + tt;
        }
        v[0] += __shfl_xor(v[0], 2);
        v[0] += __shfl_xor(v[0], 1);
        if ((l & 3) == 0){
          int m_local = kg*4 + ((l >> 3) & 1)*2 + ((l >> 2) & 1);
          s_zpart[e][ot*32 + mt*16 + m_local] = v[0];
        }
      }
    }
    __syncthreads();

    // ---- phase C: softmax (all lanes) + weighted-t, both elements ----
    #pragma unroll
    for (int e = 0; e < 2; ++e){
      float z  = s_zpart[e][o] + s_zpart[e][32 + o];
      float mx = z;
      #pragma unroll
      for (int s = 16; s > 0; s >>= 1) mx = fmaxf(mx, __shfl_xor(mx, s));
      float ex = __expf(z - mx);
      float sm = ex;
      #pragma unroll
      for (int s = 16; s > 0; s >>= 1) sm += __shfl_xor(sm, s);
      float gval = ex / sm;
      float po = 0.f;
      #pragma unroll
      for (int ml = 0; ml < 4; ++ml)
        po += __shfl(gval, g*4 + ml) * (e == 0 ? tvA[ml] : tvB[ml]);
      po += __shfl_xor(po, 32);
      if (l < 32) s_opart[e][w*32 + o] = po;
    }
    __syncthreads();

    // ---- phase D: GRU gates, weights loaded once for both elements ----
    {
      const int cc = (tid & 7) * 4;
      const int rr = tid >> 3;
      float4 oA = make_float4(0,0,0,0), oB = make_float4(0,0,0,0);
      #pragma unroll
      for (int gg = 0; gg < 4; ++gg){
        float4 ta = *(const float4*)&s_opart[0][gg*32 + cc];
        float4 tb = *(const float4*)&s_opart[1][gg*32 + cc];
        oA.x += ta.x; oA.y += ta.y; oA.z += ta.z; oA.w += ta.w;
        oB.x += tb.x; oB.y += tb.y; oB.z += tb.z; oB.w += tb.w;
      }
      float4 mA = *(const float4*)&s_M[0][cc];
      float4 mB = *(const float4*)&s_M[1][cc];
      #pragma unroll
      for (int k = 0; k < 3; ++k){
        int row = k*32 + rr;
        float4 wi = *(const float4*)(gru_w_ih + ((size_t)hop*96 + row)*32 + cc);
        float4 wh = *(const float4*)(gru_w_hh + ((size_t)hop*96 + row)*32 + cc);
        float aiA = wi.x*oA.x + wi.y*oA.y + wi.z*oA.z + wi.w*oA.w;
        float ahA = wh.x*mA.x + wh.y*mA.y + wh.z*mA.z + wh.w*mA.w;
        float aiB = wi.x*oB.x + wi.y*oB.y + wi.z*oB.z + wi.w*oB.w;
        float ahB = wh.x*mB.x + wh.y*mB.y + wh.z*mB.z + wh.w*mB.w;
        aiA += __shfl_xor(aiA,1); aiA += __shfl_xor(aiA,2); aiA += __shfl_xor(aiA,4);
        ahA += __shfl_xor(ahA,1); ahA += __shfl_xor(ahA,2); ahA += __shfl_xor(ahA,4);
        aiB += __shfl_xor(aiB,1); aiB += __shfl_xor(aiB,2); aiB += __shfl_xor(aiB,4);
        ahB += __shfl_xor(ahB,1); ahB += __shfl_xor(ahB,2); ahB += __shfl_xor(ahB,4);
        if ((tid & 7) == 0){
          s_gig[0][row]      = aiA;
          s_gig[0][96 + row] = ahA;
          s_gig[1][row]      = aiB;
          s_gig[1][96 + row] = ahB;
        }
      }
    }
    __syncthreads();

    // ---- phase E: GRU update — lanes 0-31 elem A, 32-63 elem B ----
    if (tid < 64){
      int e = tid >> 5, oo = tid & 31;
      const float* bih = gru_b_ih + hop*96;
      const float* bhh = gru_b_hh + hop*96;
      float ir = s_gig[e][oo]       + bih[oo];
      float iz = s_gig[e][32 + oo]  + bih[32 + oo];
      float in_= s_gig[e][64 + oo]  + bih[64 + oo];
      float hr = s_gig[e][96 + oo]  + bhh[oo];
      float hz = s_gig[e][128 + oo] + bhh[32 + oo];
      float hn = s_gig[e][160 + oo] + bhh[64 + oo];
      float r  = sigmoid_f(ir + hr);
      float zz = sigmoid_f(iz + hz);
      float n  = tanh_f(in_ + r*hn);
      float Mn = (1.f - zz)*n + zz*s_M[e][oo];
      s_M[e][oo] = Mn;
      s_vsM[e][oo*2+1] = Mn;
    }
    __syncthreads();
  }

  // ---- epilogue: Mw = sigmoid(M @ ans_w.T + ans_b); out = vs . Mw ----
  #pragma unroll
  for (int e = 0; e < 2; ++e){
    const int cc = (tid & 7) * 4;
    const int rr = tid >> 3;
    float4 m4 = *(const float4*)&s_M[e][cc];
    float4 aw = *(const float4*)(ans_w + (size_t)rr*32 + cc);
    float a = aw.x*m4.x + aw.y*m4.y + aw.z*m4.z + aw.w*m4.w;
    a += __shfl_xor(a,1); a += __shfl_xor(a,2); a += __shfl_xor(a,4);
    if ((tid & 7) == 0) s_zpart[e][rr] = sigmoid_f(a + ans_b[rr]);
  }
  __syncthreads();
  if (tid < 64){
    int e = tid >> 5, oo = tid & 31;
    float val = s_vsM[e][oo*2+0] * s_zpart[e][oo];
    #pragma unroll
    for (int s = 16; s > 0; s >>= 1) val += __shfl_xor(val, s);
    if (oo == 0) out[e ? eB : eA] = val;
  }
}

// ---------------- Fallback: R13 fused kernel (ws too small) ----------------
__global__ __launch_bounds__(256) void ripple_fused(
    const int* __restrict__ h_i, const int* __restrict__ R_i, const int* __restrict__ t_i,
    const int* __restrict__ v_i,
    const float* __restrict__ entity_emb, const float* __restrict__ relation_emb,
    const float* __restrict__ agg_w1, const float* __restrict__ agg_b1,
    const float* __restrict__ agg_w2,
    const float* __restrict__ gru_w_ih, const float* __restrict__ gru_w_hh,
    const float* __restrict__ gru_b_ih, const float* __restrict__ gru_b_hh,
    const float* __restrict__ ans_w, const float* __restrict__ ans_b,
    float* __restrict__ out, int batch)
{
  __shared__ __align__(16) int   s_bfrag[8*64*4];
  __shared__ __align__(16) float s_rhA[2][2][32*33];
  __shared__ __align__(16) float s_vsM[2][64];
  __shared__ __align__(16) float s_zpart[2][64];
  __shared__ __align__(16) float s_opart[2][4*32];
  __shared__ __align__(16) float s_M[2][32];
  __shared__ __align__(16) float s_gig[2][192];

  const int bid = blockIdx.x;
  const int eA  = bid*2;
  const int eB  = (eA + 1 < batch) ? eA + 1 : eA;
  const int tid = threadIdx.x;
  const int g   = tid >> 5;
  const int o   = tid & 31;
  const int l   = tid & 63;
  const int w   = tid >> 6;
  const int c   = o & 7;
  const int r_  = o >> 3;
  const bool bb4 = (c & 4) != 0;
  const bool bb2 = (c & 2) != 0;
  const bool bb1 = (c & 1) != 0;

  #pragma unroll
  for (int k = 0; k < 2; ++k){
    int s  = tid + k*256;
    int f  = s >> 6, li = s & 63;
    int x  = f >> 1, otf = f & 1;
    const float* src = agg_w1 + (otf*16 + (li & 15))*128 + x*32 + ((li >> 4) & 3)*8;
    float4 f0 = *(const float4*)src;
    float4 f1 = *(const float4*)(src + 4);
    *(int4*)&s_bfrag[s*4] = make_int4((int)pk_bf16(f0.x, f0.y), (int)pk_bf16(f0.z, f0.w),
                                      (int)pk_bf16(f1.x, f1.y), (int)pk_bf16(f1.z, f1.w));
  }
  if (tid < 64){
    int e  = tid >> 5, oo = tid & 31;
    float v = entity_emb[(size_t)v_i[e ? eB : eA]*32 + oo];
    s_vsM[e][oo*2+0] = v; s_vsM[e][oo*2+1] = v; s_M[e][oo] = v;
  }
  {
    const int iA = c*4 + r_;
    const int bgm = g*4;
    int rAc = R_i[(eA*NHOP + 0)*32 + bgm];
    int hAc = h_i[(eA*NHOP + 0)*32 + bgm];
    int rBc = R_i[(eB*NHOP + 0)*32 + bgm];
    int hBc = h_i[(eB*NHOP + 0)*32 + bgm];
    #pragma unroll 1
    for (int it = 0; it < 8; ++it){
      const int hp = it >> 2;
      const int m  = bgm + (it & 3);
      int rAn = rAc, hAn = hAc, rBn = rBc, hBn = hBc;
      if (it < 7){
        const int nhp = (it + 1) >> 2;
        const int nm  = bgm + ((it + 1) & 3);
        rAn = R_i[(eA*NHOP + nhp)*32 + nm];
        hAn = h_i[(eA*NHOP + nhp)*32 + nm];
        rBn = R_i[(eB*NHOP + nhp)*32 + nm];
        hBn = h_i[(eB*NHOP + nhp)*32 + nm];
      }
      const float* RbA = relation_emb + (size_t)rAc*1024;
      const float* RbB = relation_emb + (size_t)rBc*1024;
      float4 hvA = *(const float4*)(entity_emb + (size_t)hAc*32 + c*4);
      float4 hvB = *(const float4*)(entity_emb + (size_t)hBc*32 + c*4);
      float pA[8], pB[8];
      #pragma unroll
      for (int q = 0; q < 8; ++q){
        float4 rv = *(const float4*)(RbA + q*128 + o*4);
        pA[q] = rv.x*hvA.x + rv.y*hvA.y + rv.z*hvA.z + rv.w*hvA.w;
      }
      #pragma unroll
      for (int q = 0; q < 8; ++q){
        float4 rv = *(const float4*)(RbB + q*128 + o*4);
        pB[q] = rv.x*hvB.x + rv.y*hvB.y + rv.z*hvB.z + rv.w*hvB.w;
      }
      float a0 = bfly8(pA, bb4, bb2, bb1);
      float a1 = bfly8(pB, bb4, bb2, bb1);
      s_rhA[0][hp][m*33 + iA] = a0;
      s_rhA[1][hp][m*33 + iA] = a1;
      rAc = rAn; hAc = hAn; rBc = rBn; hBc = hBn;
    }
  }
  __syncthreads();

  const int mt  = w >> 1, ot = w & 1;
  const int col = l & 15;
  const int kg  = l >> 4;
  const float b1o = agg_b1[ot*16 + col];
  const float w2o = agg_w2[ot*16 + col];
  i32x4 bv[4];
  #pragma unroll
  for (int x = 0; x < 4; ++x)
    bv[x] = *(const i32x4*)&s_bfrag[((x*2 + ot)*64 + l)*4];

  for (int hop = 0; hop < NHOP; ++hop){
    float tvA[4], tvB[4];
    #pragma unroll
    for (int ml = 0; ml < 4; ++ml){
      tvA[ml] = entity_emb[(size_t)t_i[(eA*NHOP + hop)*32 + g*4 + ml]*32 + o];
      tvB[ml] = entity_emb[(size_t)t_i[(eB*NHOP + hop)*32 + g*4 + ml]*32 + o];
    }
    {
      #pragma unroll
      for (int e = 0; e < 2; ++e){
        const float* rp = &s_rhA[e][hop][(mt*16 + col)*33 + kg*8];
        float4 q0 = *(const float4*)(rp);
        float4 q1 = *(const float4*)(rp + 4);
        float rh[8] = {q0.x,q0.y,q0.z,q0.w,q1.x,q1.y,q1.z,q1.w};
        unsigned aw[4][4];
        #pragma unroll
        for (int q = 0; q < 4; ++q){
          int i0 = kg*8 + 2*q;
          float2 vm0 = *(const float2*)&s_vsM[e][i0*2];
          float2 vm1 = *(const float2*)&s_vsM[e][(i0+1)*2];
          float e0 = rh[2*q], e1 = rh[2*q+1];
          aw[0][q] = pk_bf16(e0*vm0.x,        e1*vm1.x);
          aw[1][q] = pk_bf16(e0*vm0.y,        e1*vm1.y);
          aw[2][q] = pk_bf16(fabsf(e0-vm0.x), fabsf(e1-vm1.x));
          aw[3][q] = pk_bf16(fabsf(e0-vm0.y), fabsf(e1-vm1.y));
        }
        f32x4 acc = {0.f, 0.f, 0.f, 0.f};
        #pragma unroll
        for (int x = 0; x < 4; ++x){
          i32x4 av = {(int)aw[x][0], (int)aw[x][1], (int)aw[x][2], (int)aw[x][3]};
          acc = __builtin_amdgcn_mfma_f32_16x16x32_bf16(
                  __builtin_bit_cast(bf16x8s, av),
                  __builtin_bit_cast(bf16x8s, bv[x]), acc, 0, 0, 0);
        }
        float v[4];
        #pragma unroll
        for (int r = 0; r < 4; ++r) v[r] = tanh_f(acc[r] + b1o) * w2o;
        const bool b3 = (l & 8) != 0;
        #pragma unroll
        for (int k = 0; k < 2; ++k){
          float send = b3 ? v[k] : v[k+2];
          float tt = __shfl_xor(send, 8);
          v[k] = (b3 ? v[k+2] : v[k]) + tt;
        }
        const bool b2_ = (l & 4) != 0;
        {
          float send = b2_ ? v[0] : v[1];
          float tt = __shfl_xor(send, 4);
          v[0] = (b2_ ? v[1] : v[0]) + tt;
        }
        v[0] += __shfl_xor(v[0], 2);
        v[0] += __shfl_xor(v[0], 1);
        if ((l & 3) == 0){
          int m_local = kg*4 + ((l >> 3) & 1)*2 + ((l >> 2) & 1);
          s_zpart[e][ot*32 + mt*16 + m_local] = v[0];
        }
      }
    }
    __syncthreads();
    #pragma unroll
    for (int e = 0; e < 2; ++e){
      float z  = s_zpart[e][o] + s_zpart[e][32 + o];
      float mx = z;
      #pragma unroll
      for (int s = 16; s > 0; s >>= 1) mx = fmaxf(mx, __shfl_xor(mx, s));
      float ex = __expf(z - mx);
      float sm = ex;
      #pragma unroll
      for (int s = 16; s > 0; s >>= 1) sm += __shfl_xor(sm, s);
      float gval = ex / sm;
      float po = 0.f;
      #pragma unroll
      for (int ml = 0; ml < 4; ++ml)
        po += __shfl(gval, g*4 + ml) * (e == 0 ? tvA[ml] : tvB[ml]);
      po += __shfl_xor(po, 32);
      if (l < 32) s_opart[e][w*32 + o] = po;
    }
    __syncthreads();
    {
      const int cc = (tid & 7) * 4;
      const int rr = tid >> 3;
      float4 oA = make_float4(0,0,0,0), oB = make_float4(0,0,0,0);
      #pragma unroll
      for (int gg = 0; gg < 4; ++gg){
        float4 ta = *(const float4*)&s_opart[0][gg*32 + cc];
        float4 tb = *(const float4*)&s_opart[1][gg*32 + cc];
        oA.x += ta.x; oA.y += ta.y; oA.z += ta.z; oA.w += ta.w;
        oB.x += tb.x; oB.y += tb.y; oB.z += tb.z; oB.w += tb.w;
      }
      float4 mA = *(const float4*)&s_M[0][cc];
      float4 mB = *(const float4*)&s_M[1][cc];
      #pragma unroll
      for (int k = 0; k < 3; ++k){
        int row = k*32 + rr;
        float4 wi = *(const float4*)(gru_w_ih + ((size_t)hop*96 + row)*32 + cc);
        float4 wh = *(const float4*)(gru_w_hh + ((size_t)hop*96 + row)*32 + cc);
        float aiA = wi.x*oA.x + wi.y*oA.y + wi.z*oA.z + wi.w*oA.w;
        float ahA = wh.x*mA.x + wh.y*mA.y + wh.z*mA.z + wh.w*mA.w;
        float aiB = wi.x*oB.x + wi.y*oB.y + wi.z*oB.z + wi.w*oB.w;
        float ahB = wh.x*mB.x + wh.y*mB.y + wh.z*mB.z + wh.w*mB.w;
        aiA += __shfl_xor(aiA,1); aiA += __shfl_xor(aiA,2); aiA += __shfl_xor(aiA,4);
        ahA += __shfl_xor(ahA,1); ahA += __shfl_xor(ahA,2); ahA += __shfl_xor(ahA,4);
        aiB += __shfl_xor(aiB,1); aiB += __shfl_xor(aiB,2); aiB += __shfl_xor(aiB,4);
        ahB += __shfl_xor(ahB,1); ahB += __shfl_xor(ahB,2); ahB += __shfl_xor(ahB,4);
        if ((tid & 7) == 0){
          s_gig[0][row]      = aiA;
          s_gig[0][96 + row] = ahA;
          s_gig[1][row]      = aiB;
          s_gig[1][96 + row] = ahB;
        }
      }
    }
    __syncthreads();
    if (tid < 64){
      int e = tid >> 5, oo = tid & 31;
      const float* bih = gru_b_ih + hop*96;
      const float* bhh = gru_b_hh + hop*96;
      float ir = s_gig[e][oo]       + bih[oo];
      float iz = s_gig[e][32 + oo]  + bih[32 + oo];
      float in_= s_gig[e][64 + oo]  + bih[64 + oo];
      float hr = s_gig[e][96 + oo]  + bhh[oo];
      float hz = s_gig[e][128 + oo] + bhh[32 + oo];
      float hn = s_gig[e][160 + oo] + bhh[64 + oo];
      float r  = sigmoid_f(ir + hr);
      float zz = sigmoid_f(iz + hz);
      float n  = tanh_f(in_ + r*hn);
      float Mn = (1.f - zz)*n + zz*s_M[e][oo];
      s_M[e][oo] = Mn;
      s_vsM[e][oo*2+1] = Mn;
    }
    __syncthreads();
  }
  #pragma unroll
  for (int e = 0; e < 2; ++e){
    const int cc = (tid & 7) * 4;
    const int rr = tid >> 3;
    float4 m4 = *(const float4*)&s_M[e][cc];
    float4 aw = *(const float4*)(ans_w + (size_t)rr*32 + cc);
    float a = aw.x*m4.x + aw.y*m4.y + aw.z*m4.z + aw.w*m4.w;
    a += __shfl_xor(a,1); a += __shfl_xor(a,2); a += __shfl_xor(a,4);
    if ((tid & 7) == 0) s_zpart[e][rr] = sigmoid_f(a + ans_b[rr]);
  }
  __syncthreads();
  if (tid < 64){
    int e = tid >> 5, oo = tid & 31;
    float val = s_vsM[e][oo*2+0] * s_zpart[e][oo];
    #pragma unroll
    for (int s = 16; s > 0; s >>= 1) val += __shfl_xor(val, s);
    if (oo == 0) out[e ? eB : eA] = val;
  }
}

extern "C" void kernel_launch(void* const* d_in, const int* in_sizes, int n_in,
                              void* d_out, int out_size, void* d_ws, size_t ws_size,
                              hipStream_t stream) {
  const int*   h_i          = (const int*)  d_in[0];
  const int*   R_i          = (const int*)  d_in[1];
  const int*   t_i          = (const int*)  d_in[2];
  const int*   v_i          = (const int*)  d_in[3];
  const float* entity_emb   = (const float*)d_in[4];
  const float* relation_emb = (const float*)d_in[5];
  const float* agg_w1       = (const float*)d_in[6];
  const float* agg_b1       = (const float*)d_in[7];
  const float* agg_w2       = (const float*)d_in[8];
  const float* gru_w_ih     = (const float*)d_in[10];
  const float* gru_w_hh     = (const float*)d_in[11];
  const float* gru_b_ih     = (const float*)d_in[12];
  const float* gru_b_hh     = (const float*)d_in[13];
  const float* ans_w        = (const float*)d_in[14];
  const float* ans_b        = (const float*)d_in[15];
  float* outp = (float*)d_out;

  const int batch = in_sizes[3];
  const int ntask = batch * NHOP * 32;
  const size_t need = (size_t)ntask * 32 * sizeof(float);

  if (ws_size >= need) {
    float* ws = (float*)d_ws;
    rh_gemv<<<(ntask + 7) / 8, 256, 0, stream>>>(
        h_i, R_i, entity_emb, relation_emb, ws, ntask);
    ripple_main<<<(batch + 1) / 2, 256, 0, stream>>>(
        t_i, v_i, entity_emb, agg_w1, agg_b1, agg_w2,
        gru_w_ih, gru_w_hh, gru_b_ih, gru_b_hh,
        ans_w, ans_b, ws, outp, batch);
  } else {
    ripple_fused<<<(batch + 1) / 2, 256, 0, stream>>>(
        h_i, R_i, t_i, v_i, entity_emb, relation_emb,
        agg_w1, agg_b1, agg_w2,
        gru_w_ih, gru_w_hh, gru_b_ih, gru_b_hh,
        ans_w, ans_b, outp, batch);
  }
}

// Round 15
// 42.749 us; speedup vs baseline: 1.1992x; 1.1992x over previous
//
#include <hip/hip_runtime.h>
#include <hip/hip_bf16.h>

// RippleNetPlus fused — round 15: 1 element/block, 8 blocks/CU (32 waves/CU),
// with R13's phase-A quality. DIM=32, HOP=2, MEM=32, grid 2048.
// R14 lesson: ws round-trip + extra dispatch + harness ws-poisoning >> saved
// latency — keep everything in one kernel, d_ws unused.
// vs R13 (41.0us, 2-elem, 4 blocks/CU): trade barrier amortization for 2x
// resident waves (TLP latency hiding the allocator can't refuse).
//  - phase A: dual-HOP streams, 4 iterations, idx prefetched 1 ahead.
//  - phase C: xor32 in-wave combine -> s_opart[4][32].
//  - bv NOT hoisted (keeps VGPR<=64 -> 8 waves/SIMD; R10 baseline was 44).
// LDS 18.6KB -> 8 blocks/CU (148.5KB/CU).

#define NHOP 2

typedef __attribute__((ext_vector_type(4)))  float f32x4;
typedef __attribute__((ext_vector_type(8)))  short bf16x8s;
typedef __attribute__((ext_vector_type(4)))  int   i32x4;

__device__ __forceinline__ float sigmoid_f(float x){ return 1.0f/(1.0f+__expf(-x)); }
__device__ __forceinline__ float tanh_f(float x){
  float e = __expf(2.0f*x);
  return 1.0f - 2.0f/(e + 1.0f);
}
__device__ __forceinline__ unsigned pk_bf16(float lo, float hi){
  __hip_bfloat162 h = __float22bfloat162_rn(make_float2(lo, hi));
  return *reinterpret_cast<unsigned*>(&h);
}
__device__ __forceinline__ float bfly8(float p[8], bool bb4, bool bb2, bool bb1){
  #pragma unroll
  for (int k = 0; k < 4; ++k){
    float send = bb4 ? p[k] : p[k+4];
    float t = __shfl_xor(send, 4);
    p[k] = (bb4 ? p[k+4] : p[k]) + t;
  }
  #pragma unroll
  for (int k = 0; k < 2; ++k){
    float send = bb2 ? p[k] : p[k+2];
    float t = __shfl_xor(send, 2);
    p[k] = (bb2 ? p[k+2] : p[k]) + t;
  }
  float send = bb1 ? p[0] : p[1];
  float t = __shfl_xor(send, 1);
  return (bb1 ? p[1] : p[0]) + t;
}

__global__ __launch_bounds__(256) void ripple_fused(
    const int* __restrict__ h_i, const int* __restrict__ R_i, const int* __restrict__ t_i,
    const int* __restrict__ v_i,
    const float* __restrict__ entity_emb, const float* __restrict__ relation_emb,
    const float* __restrict__ agg_w1, const float* __restrict__ agg_b1,
    const float* __restrict__ agg_w2,
    const float* __restrict__ gru_w_ih, const float* __restrict__ gru_w_hh,
    const float* __restrict__ gru_b_ih, const float* __restrict__ gru_b_hh,
    const float* __restrict__ ans_w, const float* __restrict__ ans_b,
    float* __restrict__ out)
{
  __shared__ __align__(16) int   s_bfrag[8*64*4];   // 8 KB   B-frags
  __shared__ __align__(16) float s_rhA[2][32*33];   // 8.25KB [hop] stride-33
  __shared__ __align__(16) float s_vsM[64];         // [i]{vs,M}
  __shared__ __align__(16) float s_zpart[64];       // [ot][m]
  __shared__ __align__(16) float s_opart[4*32];     // [wave][o]
  __shared__ __align__(16) float s_M[32];
  __shared__ __align__(16) float s_gig[192];        // gi[0:96] gh[96:192]

  const int b   = blockIdx.x;
  const int tid = threadIdx.x;
  const int g   = tid >> 5;   // group 0..7
  const int o   = tid & 31;
  const int l   = tid & 63;   // lane
  const int w   = tid >> 6;   // wave 0..3
  const int c   = o & 7;
  const int r_  = o >> 3;
  const bool bb4 = (c & 4) != 0;
  const bool bb2 = (c & 2) != 0;
  const bool bb1 = (c & 1) != 0;

  const int ib0 = (b*NHOP + 0)*32;
  const int ib1 = (b*NHOP + 1)*32;

  // ---- init: stage B-fragments (16x16x32 layout; verified R10-R13) ----
  #pragma unroll
  for (int k = 0; k < 2; ++k){
    int s  = tid + k*256;           // 0..511
    int f  = s >> 6, li = s & 63;
    int x  = f >> 1, otf = f & 1;
    const float* src = agg_w1 + (otf*16 + (li & 15))*128 + x*32 + ((li >> 4) & 3)*8;
    float4 f0 = *(const float4*)src;
    float4 f1 = *(const float4*)(src + 4);
    *(int4*)&s_bfrag[s*4] = make_int4((int)pk_bf16(f0.x, f0.y), (int)pk_bf16(f0.z, f0.w),
                                      (int)pk_bf16(f1.x, f1.y), (int)pk_bf16(f1.z, f1.w));
  }
  if (tid < 32){
    float v = entity_emb[(size_t)v_i[b]*32 + o];
    s_vsM[o*2+0] = v; s_vsM[o*2+1] = v; s_M[o] = v;
  }

  // ---- phase A: dual-HOP streams, 4 iterations, idx prefetched 1 ahead ----
  {
    const int iA  = c*4 + r_;
    const int bgm = g*4;
    int r0c = R_i[ib0 + bgm], h0c = h_i[ib0 + bgm];
    int r1c = R_i[ib1 + bgm], h1c = h_i[ib1 + bgm];
    #pragma unroll 1
    for (int ml = 0; ml < 4; ++ml){
      int r0n = r0c, h0n = h0c, r1n = r1c, h1n = h1c;
      if (ml < 3){
        r0n = R_i[ib0 + bgm + ml + 1]; h0n = h_i[ib0 + bgm + ml + 1];
        r1n = R_i[ib1 + bgm + ml + 1]; h1n = h_i[ib1 + bgm + ml + 1];
      }
      const float* Rb0 = relation_emb + (size_t)r0c*1024;
      const float* Rb1 = relation_emb + (size_t)r1c*1024;
      float4 hv0 = *(const float4*)(entity_emb + (size_t)h0c*32 + c*4);
      float4 hv1 = *(const float4*)(entity_emb + (size_t)h1c*32 + c*4);
      float p0[8], p1[8];
      #pragma unroll
      for (int q = 0; q < 8; ++q){
        float4 rv = *(const float4*)(Rb0 + q*128 + o*4);
        p0[q] = rv.x*hv0.x + rv.y*hv0.y + rv.z*hv0.z + rv.w*hv0.w;
      }
      #pragma unroll
      for (int q = 0; q < 8; ++q){
        float4 rv = *(const float4*)(Rb1 + q*128 + o*4);
        p1[q] = rv.x*hv1.x + rv.y*hv1.y + rv.z*hv1.z + rv.w*hv1.w;
      }
      float a0 = bfly8(p0, bb4, bb2, bb1);
      float a1 = bfly8(p1, bb4, bb2, bb1);
      const int m = bgm + ml;
      s_rhA[0][m*33 + iA] = a0;
      s_rhA[1][m*33 + iA] = a1;
      r0c = r0n; h0c = h0n; r1c = r1n; h1c = h1n;
    }
  }
  __syncthreads();

  // per-wave tile coords (phase B)
  const int mt  = w >> 1, ot = w & 1;
  const int col = l & 15;
  const int kg  = l >> 4;
  const float b1o = agg_b1[ot*16 + col];
  const float w2o = agg_w2[ot*16 + col];

  for (int hop = 0; hop < NHOP; ++hop){
    const int ibase = hop ? ib1 : ib0;

    // ---- t-row prefetch (hides under phase B) ----
    float tv[4];
    #pragma unroll
    for (int ml = 0; ml < 4; ++ml)
      tv[ml] = entity_emb[(size_t)t_i[ibase + g*4 + ml]*32 + o];

    // ---- phase B: wave-private 16x16 tile, 4x mfma_16x16x32 ----
    {
      const float* rp = &s_rhA[hop][(mt*16 + col)*33 + kg*8];
      float4 q0 = *(const float4*)(rp);
      float4 q1 = *(const float4*)(rp + 4);
      float rh[8] = {q0.x,q0.y,q0.z,q0.w,q1.x,q1.y,q1.z,q1.w};
      unsigned aw[4][4];
      #pragma unroll
      for (int q = 0; q < 4; ++q){
        int i0 = kg*8 + 2*q;
        float2 vm0 = *(const float2*)&s_vsM[i0*2];
        float2 vm1 = *(const float2*)&s_vsM[(i0+1)*2];
        float e0 = rh[2*q], e1 = rh[2*q+1];
        aw[0][q] = pk_bf16(e0*vm0.x,        e1*vm1.x);
        aw[1][q] = pk_bf16(e0*vm0.y,        e1*vm1.y);
        aw[2][q] = pk_bf16(fabsf(e0-vm0.x), fabsf(e1-vm1.x));
        aw[3][q] = pk_bf16(fabsf(e0-vm0.y), fabsf(e1-vm1.y));
      }
      f32x4 acc = {0.f, 0.f, 0.f, 0.f};
      #pragma unroll
      for (int x = 0; x < 4; ++x){
        i32x4 av = {(int)aw[x][0], (int)aw[x][1], (int)aw[x][2], (int)aw[x][3]};
        i32x4 bv = *(const i32x4*)&s_bfrag[((x*2 + ot)*64 + l)*4];
        acc = __builtin_amdgcn_mfma_f32_16x16x32_bf16(
                __builtin_bit_cast(bf16x8s, av),
                __builtin_bit_cast(bf16x8s, bv), acc, 0, 0, 0);
      }
      float v[4];
      #pragma unroll
      for (int r = 0; r < 4; ++r) v[r] = tanh_f(acc[r] + b1o) * w2o;
      const bool b3 = (l & 8) != 0;
      #pragma unroll
      for (int k = 0; k < 2; ++k){
        float send = b3 ? v[k] : v[k+2];
        float tt = __shfl_xor(send, 8);
        v[k] = (b3 ? v[k+2] : v[k]) + tt;
      }
      const bool b2_ = (l & 4) != 0;
      {
        float send = b2_ ? v[0] : v[1];
        float tt = __shfl_xor(send, 4);
        v[0] = (b2_ ? v[1] : v[0]) + tt;
      }
      v[0] += __shfl_xor(v[0], 2);
      v[0] += __shfl_xor(v[0], 1);
      if ((l & 3) == 0){
        int m_local = kg*4 + ((l >> 3) & 1)*2 + ((l >> 2) & 1);
        s_zpart[ot*32 + mt*16 + m_local] = v[0];
      }
    }
    __syncthreads();

    // ---- phase C: softmax (all lanes); xor32 combine -> 4 wave partials ----
    {
      float z  = s_zpart[o] + s_zpart[32 + o];
      float mx = z;
      #pragma unroll
      for (int s = 16; s > 0; s >>= 1) mx = fmaxf(mx, __shfl_xor(mx, s));
      float ex = __expf(z - mx);
      float sm = ex;
      #pragma unroll
      for (int s = 16; s > 0; s >>= 1) sm += __shfl_xor(sm, s);
      float gval = ex / sm;
      float po = 0.f;
      #pragma unroll
      for (int ml = 0; ml < 4; ++ml)
        po += __shfl(gval, g*4 + ml) * tv[ml];
      po += __shfl_xor(po, 32);
      if (l < 32) s_opart[w*32 + o] = po;
    }
    __syncthreads();

    // ---- phase D: GRU gates, distributed over 256 threads ----
    {
      const int cc = (tid & 7) * 4;
      const int rr = tid >> 3;
      float4 o4 = make_float4(0,0,0,0);
      #pragma unroll
      for (int gg = 0; gg < 4; ++gg){
        float4 t = *(const float4*)&s_opart[gg*32 + cc];
        o4.x += t.x; o4.y += t.y; o4.z += t.z; o4.w += t.w;
      }
      float4 m4 = *(const float4*)&s_M[cc];
      #pragma unroll
      for (int k = 0; k < 3; ++k){
        int row = k*32 + rr;
        float4 wi = *(const float4*)(gru_w_ih + ((size_t)hop*96 + row)*32 + cc);
        float4 wh = *(const float4*)(gru_w_hh + ((size_t)hop*96 + row)*32 + cc);
        float ai = wi.x*o4.x + wi.y*o4.y + wi.z*o4.z + wi.w*o4.w;
        float ah = wh.x*m4.x + wh.y*m4.y + wh.z*m4.z + wh.w*m4.w;
        ai += __shfl_xor(ai,1); ai += __shfl_xor(ai,2); ai += __shfl_xor(ai,4);
        ah += __shfl_xor(ah,1); ah += __shfl_xor(ah,2); ah += __shfl_xor(ah,4);
        if ((tid & 7) == 0){
          s_gig[row]      = ai;
          s_gig[96 + row] = ah;
        }
      }
    }
    __syncthreads();

    // ---- phase E: GRU state update (lanes 0..31) ----
    if (tid < 32){
      const float* bih = gru_b_ih + hop*96;
      const float* bhh = gru_b_hh + hop*96;
      float ir = s_gig[o]       + bih[o];
      float iz = s_gig[32 + o]  + bih[32 + o];
      float in_= s_gig[64 + o]  + bih[64 + o];
      float hr = s_gig[96 + o]  + bhh[o];
      float hz = s_gig[128 + o] + bhh[32 + o];
      float hn = s_gig[160 + o] + bhh[64 + o];
      float r  = sigmoid_f(ir + hr);
      float zz = sigmoid_f(iz + hz);
      float n  = tanh_f(in_ + r*hn);
      float Mn = (1.f - zz)*n + zz*s_M[o];
      s_M[o] = Mn;
      s_vsM[o*2+1] = Mn;
    }
    __syncthreads();
  }

  // ---- epilogue: Mw = sigmoid(M @ ans_w.T + ans_b); out = vs . Mw ----
  {
    const int cc = (tid & 7) * 4;
    const int rr = tid >> 3;
    float4 m4 = *(const float4*)&s_M[cc];
    float4 aw = *(const float4*)(ans_w + (size_t)rr*32 + cc);
    float a = aw.x*m4.x + aw.y*m4.y + aw.z*m4.z + aw.w*m4.w;
    a += __shfl_xor(a,1); a += __shfl_xor(a,2); a += __shfl_xor(a,4);
    if ((tid & 7) == 0) s_zpart[rr] = sigmoid_f(a + ans_b[rr]);
  }
  __syncthreads();
  if (tid < 32){
    float val = s_vsM[o*2+0] * s_zpart[o];
    #pragma unroll
    for (int s = 16; s > 0; s >>= 1) val += __shfl_xor(val, s);
    if (tid == 0) out[b] = val;
  }
}

extern "C" void kernel_launch(void* const* d_in, const int* in_sizes, int n_in,
                              void* d_out, int out_size, void* d_ws, size_t ws_size,
                              hipStream_t stream) {
  const int*   h_i          = (const int*)  d_in[0];
  const int*   R_i          = (const int*)  d_in[1];
  const int*   t_i          = (const int*)  d_in[2];
  const int*   v_i          = (const int*)  d_in[3];
  const float* entity_emb   = (const float*)d_in[4];
  const float* relation_emb = (const float*)d_in[5];
  const float* agg_w1       = (const float*)d_in[6];
  const float* agg_b1       = (const float*)d_in[7];
  const float* agg_w2       = (const float*)d_in[8];
  const float* gru_w_ih     = (const float*)d_in[10];
  const float* gru_w_hh     = (const float*)d_in[11];
  const float* gru_b_ih     = (const float*)d_in[12];
  const float* gru_b_hh     = (const float*)d_in[13];
  const float* ans_w        = (const float*)d_in[14];
  const float* ans_b        = (const float*)d_in[15];
  float* outp = (float*)d_out;

  const int batch = in_sizes[3];
  ripple_fused<<<batch, 256, 0, stream>>>(
      h_i, R_i, t_i, v_i, entity_emb, relation_emb,
      agg_w1, agg_b1, agg_w2,
      gru_w_ih, gru_w_hh, gru_b_ih, gru_b_hh,
      ans_w, ans_b, outp);
}

// Round 16
// 40.840 us; speedup vs baseline: 1.2553x; 1.0468x over previous
//
#include <hip/hip_runtime.h>
#include <hip/hip_bf16.h>

// RippleNetPlus fused — 1 block (256 thr) per TWO batch elements.
// DIM=32, HOP=2, MEM=32, BATCH=2048 -> grid 1024 = 4 blocks/CU.
//
// Round 16: R13 (41.0us verified) + phase D/E fusion.
//  - After D's 8-lane xor-reductions, thread tid=8*oo holds ALL 6 gate
//    values (rows oo,32+oo,64+oo of gi,gh as k=0..2 named regs) -> GRU
//    update computed in-place: s_gig removed, one barrier/hop saved (4->3).
//  - s_M double-buffered by hop parity (s_Mbuf[2]) to kill the D-read vs
//    fused-E-write cross-wave race.
//  - GRU weight float4s (wi/wh, 6 per thread) prefetched right after the
//    B-barrier; their L2 latency hides under phase C.
// Everything else byte-identical to R13.

#define NHOP 2

typedef __attribute__((ext_vector_type(4)))  float f32x4;
typedef __attribute__((ext_vector_type(8)))  short bf16x8s;
typedef __attribute__((ext_vector_type(4)))  int   i32x4;

__device__ __forceinline__ float sigmoid_f(float x){ return 1.0f/(1.0f+__expf(-x)); }
__device__ __forceinline__ float tanh_f(float x){
  float e = __expf(2.0f*x);
  return 1.0f - 2.0f/(e + 1.0f);
}
__device__ __forceinline__ unsigned pk_bf16(float lo, float hi){
  __hip_bfloat162 h = __float22bfloat162_rn(make_float2(lo, hi));
  return *reinterpret_cast<unsigned*>(&h);
}
__device__ __forceinline__ float bfly8(float p[8], bool bb4, bool bb2, bool bb1){
  #pragma unroll
  for (int k = 0; k < 4; ++k){
    float send = bb4 ? p[k] : p[k+4];
    float t = __shfl_xor(send, 4);
    p[k] = (bb4 ? p[k+4] : p[k]) + t;
  }
  #pragma unroll
  for (int k = 0; k < 2; ++k){
    float send = bb2 ? p[k] : p[k+2];
    float t = __shfl_xor(send, 2);
    p[k] = (bb2 ? p[k+2] : p[k]) + t;
  }
  float send = bb1 ? p[0] : p[1];
  float t = __shfl_xor(send, 1);
  return (bb1 ? p[1] : p[0]) + t;
}

__global__ __launch_bounds__(256) void ripple_fused(
    const int* __restrict__ h_i, const int* __restrict__ R_i, const int* __restrict__ t_i,
    const int* __restrict__ v_i,
    const float* __restrict__ entity_emb, const float* __restrict__ relation_emb,
    const float* __restrict__ agg_w1, const float* __restrict__ agg_b1,
    const float* __restrict__ agg_w2,
    const float* __restrict__ gru_w_ih, const float* __restrict__ gru_w_hh,
    const float* __restrict__ gru_b_ih, const float* __restrict__ gru_b_hh,
    const float* __restrict__ ans_w, const float* __restrict__ ans_b,
    float* __restrict__ out, int batch)
{
  __shared__ __align__(16) int   s_bfrag[8*64*4];     // 8 KB   shared B-frags
  __shared__ __align__(16) float s_rhA[2][2][32*33];  // 16.5KB [elem][hop] stride-33
  __shared__ __align__(16) float s_vsM[2][64];        // [elem][i*2+{vs,M}]
  __shared__ __align__(16) float s_zpart[2][64];      // [elem][ot*32+m]
  __shared__ __align__(16) float s_opart[2][4*32];    // [elem][w][o]
  __shared__ __align__(16) float s_Mbuf[2][2][32];    // [hop-parity][elem][o]

  const int bid = blockIdx.x;
  const int eA  = bid*2;
  const int eB  = (eA + 1 < batch) ? eA + 1 : eA;
  const int tid = threadIdx.x;
  const int g   = tid >> 5;   // group 0..7
  const int o   = tid & 31;
  const int l   = tid & 63;   // lane
  const int w   = tid >> 6;   // wave 0..3
  const int c   = o & 7;
  const int r_  = o >> 3;
  const bool bb4 = (c & 4) != 0;
  const bool bb2 = (c & 2) != 0;
  const bool bb1 = (c & 1) != 0;

  // ---- init: stage B-fragments (16x16x32 layout; verified R10..R13) ----
  #pragma unroll
  for (int k = 0; k < 2; ++k){
    int s  = tid + k*256;           // 0..511
    int f  = s >> 6, li = s & 63;
    int x  = f >> 1, otf = f & 1;
    const float* src = agg_w1 + (otf*16 + (li & 15))*128 + x*32 + ((li >> 4) & 3)*8;
    float4 f0 = *(const float4*)src;
    float4 f1 = *(const float4*)(src + 4);
    *(int4*)&s_bfrag[s*4] = make_int4((int)pk_bf16(f0.x, f0.y), (int)pk_bf16(f0.z, f0.w),
                                      (int)pk_bf16(f1.x, f1.y), (int)pk_bf16(f1.z, f1.w));
  }
  if (tid < 64){
    int e  = tid >> 5, oo = tid & 31;
    float v = entity_emb[(size_t)v_i[e ? eB : eA]*32 + oo];
    s_vsM[e][oo*2+0] = v; s_vsM[e][oo*2+1] = v; s_Mbuf[0][e][oo] = v;
  }

  // ---- phase A (both hops x both elems): dual-chain Rh gather with
  //      index loads pipelined one iteration ahead (R13-verified) ----
  {
    const int iA = c*4 + r_;
    const int bgm = g*4;
    int rAc = R_i[(eA*NHOP + 0)*32 + bgm];
    int hAc = h_i[(eA*NHOP + 0)*32 + bgm];
    int rBc = R_i[(eB*NHOP + 0)*32 + bgm];
    int hBc = h_i[(eB*NHOP + 0)*32 + bgm];
    #pragma unroll 1
    for (int it = 0; it < 8; ++it){
      const int hp = it >> 2;
      const int m  = bgm + (it & 3);
      int rAn = rAc, hAn = hAc, rBn = rBc, hBn = hBc;
      if (it < 7){
        const int nhp = (it + 1) >> 2;
        const int nm  = bgm + ((it + 1) & 3);
        rAn = R_i[(eA*NHOP + nhp)*32 + nm];
        hAn = h_i[(eA*NHOP + nhp)*32 + nm];
        rBn = R_i[(eB*NHOP + nhp)*32 + nm];
        hBn = h_i[(eB*NHOP + nhp)*32 + nm];
      }
      const float* RbA = relation_emb + (size_t)rAc*1024;
      const float* RbB = relation_emb + (size_t)rBc*1024;
      float4 hvA = *(const float4*)(entity_emb + (size_t)hAc*32 + c*4);
      float4 hvB = *(const float4*)(entity_emb + (size_t)hBc*32 + c*4);
      float pA[8], pB[8];
      #pragma unroll
      for (int q = 0; q < 8; ++q){
        float4 rv = *(const float4*)(RbA + q*128 + o*4);
        pA[q] = rv.x*hvA.x + rv.y*hvA.y + rv.z*hvA.z + rv.w*hvA.w;
      }
      #pragma unroll
      for (int q = 0; q < 8; ++q){
        float4 rv = *(const float4*)(RbB + q*128 + o*4);
        pB[q] = rv.x*hvB.x + rv.y*hvB.y + rv.z*hvB.z + rv.w*hvB.w;
      }
      float a0 = bfly8(pA, bb4, bb2, bb1);
      float a1 = bfly8(pB, bb4, bb2, bb1);
      s_rhA[0][hp][m*33 + iA] = a0;
      s_rhA[1][hp][m*33 + iA] = a1;
      rAc = rAn; hAc = hAn; rBc = rBn; hBc = hBn;
    }
  }
  __syncthreads();

  // per-wave tile coords (phase B) + hop-invariant B-fragments in registers
  const int mt  = w >> 1, ot = w & 1;
  const int col = l & 15;
  const int kg  = l >> 4;
  const float b1o = agg_b1[ot*16 + col];
  const float w2o = agg_w2[ot*16 + col];
  i32x4 bv[4];
  #pragma unroll
  for (int x = 0; x < 4; ++x)
    bv[x] = *(const i32x4*)&s_bfrag[((x*2 + ot)*64 + l)*4];

  for (int hop = 0; hop < NHOP; ++hop){
    const int cur = hop & 1, nxt = cur ^ 1;

    // ---- t-row prefetch for both elements ----
    float tvA[4], tvB[4];
    #pragma unroll
    for (int ml = 0; ml < 4; ++ml){
      tvA[ml] = entity_emb[(size_t)t_i[(eA*NHOP + hop)*32 + g*4 + ml]*32 + o];
      tvB[ml] = entity_emb[(size_t)t_i[(eB*NHOP + hop)*32 + g*4 + ml]*32 + o];
    }

    // ---- phase B: wave tile via mfma_16x16x32, both elements ----
    {
      #pragma unroll
      for (int e = 0; e < 2; ++e){
        const float* rp = &s_rhA[e][hop][(mt*16 + col)*33 + kg*8];
        float4 q0 = *(const float4*)(rp);
        float4 q1 = *(const float4*)(rp + 4);
        float rh[8] = {q0.x,q0.y,q0.z,q0.w,q1.x,q1.y,q1.z,q1.w};
        unsigned aw[4][4];
        #pragma unroll
        for (int q = 0; q < 4; ++q){
          int i0 = kg*8 + 2*q;
          float2 vm0 = *(const float2*)&s_vsM[e][i0*2];
          float2 vm1 = *(const float2*)&s_vsM[e][(i0+1)*2];
          float e0 = rh[2*q], e1 = rh[2*q+1];
          aw[0][q] = pk_bf16(e0*vm0.x,        e1*vm1.x);
          aw[1][q] = pk_bf16(e0*vm0.y,        e1*vm1.y);
          aw[2][q] = pk_bf16(fabsf(e0-vm0.x), fabsf(e1-vm1.x));
          aw[3][q] = pk_bf16(fabsf(e0-vm0.y), fabsf(e1-vm1.y));
        }
        f32x4 acc = {0.f, 0.f, 0.f, 0.f};
        #pragma unroll
        for (int x = 0; x < 4; ++x){
          i32x4 av = {(int)aw[x][0], (int)aw[x][1], (int)aw[x][2], (int)aw[x][3]};
          acc = __builtin_amdgcn_mfma_f32_16x16x32_bf16(
                  __builtin_bit_cast(bf16x8s, av),
                  __builtin_bit_cast(bf16x8s, bv[x]), acc, 0, 0, 0);
        }
        float v[4];
        #pragma unroll
        for (int r = 0; r < 4; ++r) v[r] = tanh_f(acc[r] + b1o) * w2o;
        const bool b3 = (l & 8) != 0;
        #pragma unroll
        for (int k = 0; k < 2; ++k){
          float send = b3 ? v[k] : v[k+2];
          float tt = __shfl_xor(send, 8);
          v[k] = (b3 ? v[k+2] : v[k]) + tt;
        }
        const bool b2_ = (l & 4) != 0;
        {
          float send = b2_ ? v[0] : v[1];
          float tt = __shfl_xor(send, 4);
          v[0] = (b2_ ? v[1] : v[0]) + tt;
        }
        v[0] += __shfl_xor(v[0], 2);
        v[0] += __shfl_xor(v[0], 1);
        if ((l & 3) == 0){
          int m_local = kg*4 + ((l >> 3) & 1)*2 + ((l >> 2) & 1);
          s_zpart[e][ot*32 + mt*16 + m_local] = v[0];
        }
      }
    }
    __syncthreads();

    // ---- hoisted GRU weight prefetch (independent of phase C; latency
    //      hides under the softmax) ----
    const int cc = (tid & 7) * 4;
    const int rr = tid >> 3;          // 0..31
    float4 wi_k[3], wh_k[3];
    #pragma unroll
    for (int k = 0; k < 3; ++k){
      int row = k*32 + rr;
      wi_k[k] = *(const float4*)(gru_w_ih + ((size_t)hop*96 + row)*32 + cc);
      wh_k[k] = *(const float4*)(gru_w_hh + ((size_t)hop*96 + row)*32 + cc);
    }

    // ---- phase C: softmax (all lanes) + weighted-t, both elements ----
    #pragma unroll
    for (int e = 0; e < 2; ++e){
      float z  = s_zpart[e][o] + s_zpart[e][32 + o];
      float mx = z;
      #pragma unroll
      for (int s = 16; s > 0; s >>= 1) mx = fmaxf(mx, __shfl_xor(mx, s));
      float ex = __expf(z - mx);
      float sm = ex;
      #pragma unroll
      for (int s = 16; s > 0; s >>= 1) sm += __shfl_xor(sm, s);
      float gval = ex / sm;
      float po = 0.f;
      #pragma unroll
      for (int ml = 0; ml < 4; ++ml)
        po += __shfl(gval, g*4 + ml) * (e == 0 ? tvA[ml] : tvB[ml]);
      po += __shfl_xor(po, 32);
      if (l < 32) s_opart[e][w*32 + o] = po;
    }
    __syncthreads();

    // ---- phase D+E fused: gates + in-place GRU update (no s_gig) ----
    {
      float4 o4A = make_float4(0,0,0,0), o4B = make_float4(0,0,0,0);
      #pragma unroll
      for (int gg = 0; gg < 4; ++gg){
        float4 ta = *(const float4*)&s_opart[0][gg*32 + cc];
        float4 tb = *(const float4*)&s_opart[1][gg*32 + cc];
        o4A.x += ta.x; o4A.y += ta.y; o4A.z += ta.z; o4A.w += ta.w;
        o4B.x += tb.x; o4B.y += tb.y; o4B.z += tb.z; o4B.w += tb.w;
      }
      float4 mA = *(const float4*)&s_Mbuf[cur][0][cc];
      float4 mB = *(const float4*)&s_Mbuf[cur][1][cc];
      float aiA[3], ahA[3], aiB[3], ahB[3];
      #pragma unroll
      for (int k = 0; k < 3; ++k){
        float4 wi = wi_k[k], wh = wh_k[k];
        float a0 = wi.x*o4A.x + wi.y*o4A.y + wi.z*o4A.z + wi.w*o4A.w;
        float a1 = wh.x*mA.x  + wh.y*mA.y  + wh.z*mA.z  + wh.w*mA.w;
        float a2 = wi.x*o4B.x + wi.y*o4B.y + wi.z*o4B.z + wi.w*o4B.w;
        float a3 = wh.x*mB.x  + wh.y*mB.y  + wh.z*mB.z  + wh.w*mB.w;
        a0 += __shfl_xor(a0,1); a0 += __shfl_xor(a0,2); a0 += __shfl_xor(a0,4);
        a1 += __shfl_xor(a1,1); a1 += __shfl_xor(a1,2); a1 += __shfl_xor(a1,4);
        a2 += __shfl_xor(a2,1); a2 += __shfl_xor(a2,2); a2 += __shfl_xor(a2,4);
        a3 += __shfl_xor(a3,1); a3 += __shfl_xor(a3,2); a3 += __shfl_xor(a3,4);
        aiA[k] = a0; ahA[k] = a1; aiB[k] = a2; ahB[k] = a3;
      }
      if ((tid & 7) == 0){
        const float* bih = gru_b_ih + hop*96;
        const float* bhh = gru_b_hh + hop*96;
        float bi0 = bih[rr], bi1 = bih[32+rr], bi2 = bih[64+rr];
        float bh0 = bhh[rr], bh1 = bhh[32+rr], bh2 = bhh[64+rr];
        {
          float r  = sigmoid_f(aiA[0]+bi0 + ahA[0]+bh0);
          float zz = sigmoid_f(aiA[1]+bi1 + ahA[1]+bh1);
          float n  = tanh_f(aiA[2]+bi2 + r*(ahA[2]+bh2));
          float Mn = (1.f - zz)*n + zz*s_Mbuf[cur][0][rr];
          s_Mbuf[nxt][0][rr] = Mn;
          s_vsM[0][rr*2+1]   = Mn;
        }
        {
          float r  = sigmoid_f(aiB[0]+bi0 + ahB[0]+bh0);
          float zz = sigmoid_f(aiB[1]+bi1 + ahB[1]+bh1);
          float n  = tanh_f(aiB[2]+bi2 + r*(ahB[2]+bh2));
          float Mn = (1.f - zz)*n + zz*s_Mbuf[cur][1][rr];
          s_Mbuf[nxt][1][rr] = Mn;
          s_vsM[1][rr*2+1]   = Mn;
        }
      }
    }
    __syncthreads();
  }

  // ---- epilogue: Mw = sigmoid(M @ ans_w.T + ans_b); out = vs . Mw ----
  // final M lives in s_Mbuf[0] (hop1 wrote nxt = 0)
  #pragma unroll
  for (int e = 0; e < 2; ++e){
    const int cc = (tid & 7) * 4;
    const int rr = tid >> 3;
    float4 m4 = *(const float4*)&s_Mbuf[0][e][cc];
    float4 aw = *(const float4*)(ans_w + (size_t)rr*32 + cc);
    float a = aw.x*m4.x + aw.y*m4.y + aw.z*m4.z + aw.w*m4.w;
    a += __shfl_xor(a,1); a += __shfl_xor(a,2); a += __shfl_xor(a,4);
    if ((tid & 7) == 0) s_zpart[e][rr] = sigmoid_f(a + ans_b[rr]);
  }
  __syncthreads();
  if (tid < 64){
    int e = tid >> 5, oo = tid & 31;
    float val = s_vsM[e][oo*2+0] * s_zpart[e][oo];
    #pragma unroll
    for (int s = 16; s > 0; s >>= 1) val += __shfl_xor(val, s);
    if (oo == 0) out[e ? eB : eA] = val;
  }
}

extern "C" void kernel_launch(void* const* d_in, const int* in_sizes, int n_in,
                              void* d_out, int out_size, void* d_ws, size_t ws_size,
                              hipStream_t stream) {
  const int*   h_i          = (const int*)  d_in[0];
  const int*   R_i          = (const int*)  d_in[1];
  const int*   t_i          = (const int*)  d_in[2];
  const int*   v_i          = (const int*)  d_in[3];
  const float* entity_emb   = (const float*)d_in[4];
  const float* relation_emb = (const float*)d_in[5];
  const float* agg_w1       = (const float*)d_in[6];
  const float* agg_b1       = (const float*)d_in[7];
  const float* agg_w2       = (const float*)d_in[8];
  const float* gru_w_ih     = (const float*)d_in[10];
  const float* gru_w_hh     = (const float*)d_in[11];
  const float* gru_b_ih     = (const float*)d_in[12];
  const float* gru_b_hh     = (const float*)d_in[13];
  const float* ans_w        = (const float*)d_in[14];
  const float* ans_b        = (const float*)d_in[15];
  float* outp = (float*)d_out;

  const int batch = in_sizes[3];
  const int grid  = (batch + 1) / 2;
  ripple_fused<<<grid, 256, 0, stream>>>(
      h_i, R_i, t_i, v_i, entity_emb, relation_emb,
      agg_w1, agg_b1, agg_w2,
      gru_w_ih, gru_w_hh, gru_b_ih, gru_b_hh,
      ans_w, ans_b, outp, batch);
}